// Round 1
// baseline (2312.540 us; speedup 1.0000x reference)
//
#include <hip/hip_runtime.h>
#include <hip/hip_bf16.h>

// ECLGCNN: ChebConv(K=3) on 49152 disjoint 32-node graphs -> per-sample BN ->
// sigmoid -> LSTM(48 steps, H=512) -> linear head. Inputs fp32, output fp32.
// R8: replace 48 k_step launches with ONE persistent k_lstm (2 blocks/CU).
// Inter-step sync is per-(step, m-group) counters (16 independent chains of 32
// producer tiles), release/acquire-free consumers via fresh h slabs (h_all[49])
// so L2 keeps W' warm across steps. hs buffer dropped; k_final applies sigmoid.

#define B_    1024
#define T_    48
#define NPG_  32
#define F_    5
#define H_    512
#define EPG_  256
#define NG_   (B_*T_)          // 49152 graphs
#define N_    (B_*T_*NPG_)     // 1572864 nodes
#define E_    (B_*T_*EPG_)     // 12582912 edges
#define NF_   (N_*F_)          // 7864320

typedef __bf16 bf16x8 __attribute__((ext_vector_type(8)));
typedef float  f32x4  __attribute__((ext_vector_type(4)));
typedef __hip_bfloat16 bf16;

__device__ __forceinline__ float sigm(float x)   { return 1.0f/(1.0f+__expf(-x)); }
__device__ __forceinline__ float tanh_f(float x) { return 2.0f/(1.0f+__expf(-2.0f*x)) - 1.0f; }

__device__ __forceinline__ void gl_lds16(const void* g, void* l) {
    __builtin_amdgcn_global_load_lds((const __attribute__((address_space(1))) unsigned int*)g,
                                     (__attribute__((address_space(3))) unsigned int*)l, 16, 0, 0);
}

__global__ __launch_bounds__(256) void k_zero(float4* p, int n) {
    int i = blockIdx.x*256 + threadIdx.x;
    if (i < n) p[i] = make_float4(0.f, 0.f, 0.f, 0.f);
}

// Pack W' = [Wih | Whh] row-major [2048][672], fp32 -> bf16.
__global__ __launch_bounds__(256) void k_pack(const float* __restrict__ Wih,
                                              const float* __restrict__ Whh,
                                              bf16* __restrict__ Wp) {
    int i = blockIdx.x*256 + threadIdx.x;           // < 2048*672
    int r = i / 672, c = i - r*672;
    float v = (c < 160) ? Wih[r*160 + c] : Whh[r*512 + (c-160)];
    Wp[i] = __float2bfloat16(v);
}

// Graph-per-wave ChebConv: 4 graphs per 256-thread block.
__global__ __launch_bounds__(256) void k_graph(
    const float* __restrict__ x, const float* __restrict__ ea,
    const float* __restrict__ cW, const float* __restrict__ cb,
    const int* __restrict__ ei, float* __restrict__ y_pre,
    float* __restrict__ part)
{
    const int tid = threadIdx.x, w = tid >> 6, lane = tid & 63;
    const int g = blockIdx.x*4 + w;
    __shared__ float Msh[4][1056];                  // Mt[d][s], row stride 33
    __shared__ float dinv[4][32];
    __shared__ float T0s[4][160], T1s[4][160], T2s[4][160];
    __shared__ __align__(16) float Spad[4][256];    // scaled vec, rows padded to 8
    __shared__ float Wsh[75], bsh[5];
    float* mt = Msh[w];

    if (lane < 75) Wsh[lane] = cW[lane];
    if (lane < 5)  bsh[lane] = cb[lane];
    const float4 ew = *reinterpret_cast<const float4*>(ea + (size_t)g*256 + lane*4);
    const int4   es = *reinterpret_cast<const int4*>(ei + (size_t)g*256 + lane*4);
    const int4   ed = *reinterpret_cast<const int4*>(ei + (size_t)E_ + (size_t)g*256 + lane*4);
    T0s[w][lane]      = x[(size_t)g*160 + lane];
    T0s[w][64+lane]   = x[(size_t)g*160 + 64 + lane];
    if (lane < 32) T0s[w][128+lane] = x[(size_t)g*160 + 128 + lane];
    for (int i = lane; i < 1056; i += 64) mt[i] = 0.f;
    __syncthreads();
    atomicAdd(&mt[(ed.x & 31)*33 + (es.x & 31)], ew.x);
    atomicAdd(&mt[(ed.y & 31)*33 + (es.y & 31)], ew.y);
    atomicAdd(&mt[(ed.z & 31)*33 + (es.z & 31)], ew.z);
    atomicAdd(&mt[(ed.w & 31)*33 + (es.w & 31)], ew.w);
    __syncthreads();
    if (lane < 32) {                                // deg[s] = sum_d Mt[d][s]
        float dg = 0.f;
        #pragma unroll
        for (int d = 0; d < 32; ++d) dg += mt[d*33 + lane];
        dinv[w][lane] = dg > 0.f ? rsqrtf(dg) : 0.f;
    }
    __syncthreads();
    for (int i = lane; i < 160; i += 64) Spad[w][(i/5)*8 + (i%5)] = dinv[w][i/5]*T0s[w][i];
    __syncthreads();
    if (lane < 32) {                                // T1 = -dinv .* (Mt @ S0)
        const int d = lane;
        float a0=0.f,a1=0.f,a2=0.f,a3=0.f,a4=0.f;
        #pragma unroll 4
        for (int s = 0; s < 32; ++s) {
            const float m = mt[d*33+s];
            const float4 sv = *reinterpret_cast<const float4*>(&Spad[w][s*8]);
            const float s4 = Spad[w][s*8+4];
            a0 += m*sv.x; a1 += m*sv.y; a2 += m*sv.z; a3 += m*sv.w; a4 += m*s4;
        }
        const float sc = -dinv[w][d];
        T1s[w][d*5+0]=sc*a0; T1s[w][d*5+1]=sc*a1; T1s[w][d*5+2]=sc*a2;
        T1s[w][d*5+3]=sc*a3; T1s[w][d*5+4]=sc*a4;
    }
    __syncthreads();
    for (int i = lane; i < 160; i += 64) Spad[w][(i/5)*8 + (i%5)] = dinv[w][i/5]*T1s[w][i];
    __syncthreads();
    if (lane < 32) {                                // T2 = 2 L~ T1 - T0
        const int d = lane;
        float a0=0.f,a1=0.f,a2=0.f,a3=0.f,a4=0.f;
        #pragma unroll 4
        for (int s = 0; s < 32; ++s) {
            const float m = mt[d*33+s];
            const float4 sv = *reinterpret_cast<const float4*>(&Spad[w][s*8]);
            const float s4 = Spad[w][s*8+4];
            a0 += m*sv.x; a1 += m*sv.y; a2 += m*sv.z; a3 += m*sv.w; a4 += m*s4;
        }
        const float sc = -2.f*dinv[w][d];
        T2s[w][d*5+0]=sc*a0-T0s[w][d*5+0]; T2s[w][d*5+1]=sc*a1-T0s[w][d*5+1];
        T2s[w][d*5+2]=sc*a2-T0s[w][d*5+2]; T2s[w][d*5+3]=sc*a3-T0s[w][d*5+3];
        T2s[w][d*5+4]=sc*a4-T0s[w][d*5+4];
    }
    __syncthreads();
    float* vb = mt;                                 // reuse adjacency LDS for y
    for (int i = lane; i < 160; i += 64) {
        const int n = i/5, f = i - 5*n;
        float v = bsh[f];
        #pragma unroll
        for (int c = 0; c < 5; ++c)
            v += T0s[w][n*5+c]*Wsh[c*5+f] + T1s[w][n*5+c]*Wsh[25+c*5+f] + T2s[w][n*5+c]*Wsh[50+c*5+f];
        y_pre[(size_t)g*160 + i] = v;
        vb[i] = v;
    }
    __syncthreads();
    if (lane < 10) {                                // per-graph BN partials
        const int f = lane % 5; const bool sq = lane >= 5;
        float sm = 0.f;
        #pragma unroll 8
        for (int n = 0; n < 32; ++n) { float v = vb[n*5+f]; sm += sq ? v*v : v; }
        part[(size_t)g*10 + lane] = sm;
    }
}

__global__ __launch_bounds__(64) void k_stats(const float* __restrict__ part,
                                              float* __restrict__ bn_acc) {
    const int b = blockIdx.x, tid = threadIdx.x;
    if (tid < 10) {
        float s = 0.f;
        for (int j = 0; j < T_; ++j) s += part[((size_t)b*T_ + j)*10 + tid];
        bn_acc[b*10 + tid] = s;
    }
}

__global__ __launch_bounds__(256) void k_bn(
    const float* __restrict__ y_pre, const float* __restrict__ bn_acc,
    const float* __restrict__ gamma, const float* __restrict__ beta,
    bf16* __restrict__ X)
{
    const int i = blockIdx.x*256 + threadIdx.x;
    const int b   = i / 7680;
    const int rem = i - b*7680;
    const int t   = rem / 160;
    const int pf  = rem - t*160;
    const int f   = pf % 5;
    const float inv  = 1.0f/1536.0f;
    const float mean = bn_acc[b*10+f]*inv;
    const float var  = bn_acc[b*10+5+f]*inv - mean*mean;
    const float v = gamma[f]*(y_pre[i]-mean)*rsqrtf(var+1e-5f) + beta[f];
    X[((size_t)t*B_ + b)*160 + pf] = __float2bfloat16(sigm(v));
}

// ---- persistent LSTM: 3-phase staged GEMM per step, flag-sync between steps ----
// 512 tiles (16 m-groups x 32 u-tiles). Tile (mi,ui): 64 batch rows x 64 gate
// rows. h stored in fresh slabs h_all[t] (49 x 1MB) -> consumers never re-read
// a cached address, so no acquire-invalidate; W' stays L2-warm across steps.
// Producers: release fetch_add on cnt[t][mi]; consumers spin (relaxed, s_sleep)
// until 32, overlapped with the h-independent X-phase staging.

__device__ __forceinline__ void stage_A(const char* gbase, int strideB, char* lds,
                                        int gpr, int xmask, int nper, int tid) {
    for (int p = 0; p < nper; ++p) {
        const int S = p*256 + tid;
        const int row = S / gpr;
        const int col = (S - row*gpr) ^ (row & xmask);
        gl_lds16(gbase + (size_t)row*strideB + (size_t)col*16, lds + (size_t)S*16);
    }
}

__device__ __forceinline__ void stage_W(const char* Wbase, char* lds,
                                        int gpr, int xmask, int nper, int tid, int u0) {
    for (int p = 0; p < nper; ++p) {
        const int S = p*256 + tid;
        const int row = S / gpr;
        const int col = (S - row*gpr) ^ (row & xmask);
        const int wrow = ((row >> 4) << 9) + u0 + (row & 15);
        gl_lds16(Wbase + (size_t)wrow*1344 + (size_t)col*16, lds + (size_t)S*16);
    }
}

__device__ __forceinline__ void mfma_phase(const char* Al, const char* Wl, int gpr,
                                           int xmask, int nkk, int arow, int lo,
                                           int quad, f32x4 acc[4]) {
    for (int kk = 0; kk < nkk; ++kk) {
        const int kq = kk*4 + quad;
        const bf16x8 a = *reinterpret_cast<const bf16x8*>(
            Al + ((size_t)arow*gpr + (kq ^ (arow & xmask)))*16);
        #pragma unroll
        for (int g = 0; g < 4; ++g) {
            const int wr = g*16 + lo;
            const bf16x8 b = *reinterpret_cast<const bf16x8*>(
                Wl + ((size_t)wr*gpr + (kq ^ (wr & xmask)))*16);
            acc[g] = __builtin_amdgcn_mfma_f32_16x16x32_bf16(a, b, acc[g], 0, 0, 0);
        }
    }
}

__global__ __launch_bounds__(256, 2) void k_lstm(
    const bf16* __restrict__ X,  const bf16* __restrict__ Wp,
    const float* __restrict__ bih, const float* __restrict__ bhh,
    bf16* __restrict__ h_all, float* __restrict__ c_buf,
    int* __restrict__ cnt)
{
    extern __shared__ char sm[];
    char* Al = sm;
    char* Wl = sm + 32768;
    const int tid = threadIdx.x;
    const int lane = tid & 63, w = tid >> 6;
    const int lo = lane & 15, quad = lane >> 4;
    const int arow = w*16 + lo;
    const char* Wb = (const char*)Wp;

    for (int t = 0; t < T_; ++t) {
        const char* Hin = (const char*)(h_all + (size_t)t*B_*H_);
        bf16* h_out = h_all + (size_t)(t+1)*B_*H_;
        for (int tile = blockIdx.x; tile < 512; tile += gridDim.x) {
            const int mi = tile >> 5, ui = tile & 31;
            const int m0 = mi*64, u0 = ui*16;
            const char* Xb = (const char*)X + (size_t)t*B_*320 + (size_t)m0*320;
            const char* Hb = Hin + (size_t)m0*1024;
            f32x4 acc[4] = {};

            // phase 0: X part (K=160) -- independent of h, overlaps the wait
            stage_A(Xb, 320, Al, 20, 3, 5, tid);
            stage_W(Wb, Wl, 20, 3, 5, tid, u0);
            const int u = u0 + lo;
            const float bI = bih[u]      + bhh[u];
            const float bF = bih[512+u]  + bhh[512+u];
            const float bG = bih[1024+u] + bhh[1024+u];
            const float bO = bih[1536+u] + bhh[1536+u];
            if (t > 0 && tid == 0) {                 // wait h producers of step t-1
                int* p = cnt + (t-1)*16 + mi;
                while (__hip_atomic_load(p, __ATOMIC_RELAXED, __HIP_MEMORY_SCOPE_AGENT) < 32)
                    __builtin_amdgcn_s_sleep(2);
            }
            __syncthreads();                          // drains vmcnt: LDS ready
            mfma_phase(Al, Wl, 20, 3, 5, arow, lo, quad, acc);
            __syncthreads();
            // phase 1: h[0:256)
            stage_A(Hb, 1024, Al, 32, 7, 8, tid);
            stage_W(Wb + 320, Wl, 32, 7, 8, tid, u0);
            __syncthreads();
            mfma_phase(Al, Wl, 32, 7, 8, arow, lo, quad, acc);
            __syncthreads();
            // phase 2: h[256:512)
            stage_A(Hb + 512, 1024, Al, 32, 7, 8, tid);
            stage_W(Wb + 832, Wl, 32, 7, 8, tid, u0);
            __syncthreads();
            mfma_phase(Al, Wl, 32, 7, 8, arow, lo, quad, acc);

            #pragma unroll
            for (int r = 0; r < 4; ++r) {
                const int m = m0 + w*16 + quad*4 + r;
                const int idx = m*512 + u;
                const float iv = acc[0][r] + bI;
                const float fv = acc[1][r] + bF;
                const float gv = acc[2][r] + bG;
                const float ov = acc[3][r] + bO;
                const float c_new = sigm(fv)*c_buf[idx] + sigm(iv)*tanh_f(gv);
                c_buf[idx] = c_new;
                h_out[idx] = __float2bfloat16(sigm(ov)*tanh_f(c_new));
            }
            __syncthreads();                          // all stores drained (vmcnt 0)
            if (tid == 0)                             // release: wb L2 + visible add
                __hip_atomic_fetch_add(cnt + t*16 + mi, 1,
                                       __ATOMIC_RELEASE, __HIP_MEMORY_SCOPE_AGENT);
        }
    }
}

// out[b,j] = sigmoid( sum_{t,u} sigm(h[t,b,u]) * lin_W[j, t*512+u] + lin_b[j] )
__global__ __launch_bounds__(256) void k_final(
    const bf16* __restrict__ hs, const float* __restrict__ lW,
    const float* __restrict__ lb, float* __restrict__ out)
{
    const int b = blockIdx.x, tid = threadIdx.x;
    const int u = tid*2;
    float a0=0.f, a1=0.f, a2=0.f, a3=0.f;
    for (int t = 0; t < T_; ++t) {
        const bf16* hr = hs + ((size_t)t*B_ + b)*H_ + u;
        const float h0 = sigm((float)hr[0]), h1 = sigm((float)hr[1]);
        const int o = t*H_ + u;
        a0 += h0*lW[o]         + h1*lW[o+1];
        a1 += h0*lW[24576+o]   + h1*lW[24576+o+1];
        a2 += h0*lW[49152+o]   + h1*lW[49152+o+1];
        a3 += h0*lW[73728+o]   + h1*lW[73728+o+1];
    }
    #pragma unroll
    for (int off = 32; off > 0; off >>= 1) {
        a0 += __shfl_down(a0, off, 64);
        a1 += __shfl_down(a1, off, 64);
        a2 += __shfl_down(a2, off, 64);
        a3 += __shfl_down(a3, off, 64);
    }
    __shared__ float red[4][4];
    const int wave = tid >> 6, lane = tid & 63;
    if (lane == 0) { red[0][wave]=a0; red[1][wave]=a1; red[2][wave]=a2; red[3][wave]=a3; }
    __syncthreads();
    if (tid < 4) {
        float s = red[tid][0]+red[tid][1]+red[tid][2]+red[tid][3] + lb[tid];
        out[b*4 + tid] = sigm(s);
    }
}

extern "C" void kernel_launch(void* const* d_in, const int* in_sizes, int n_in,
                              void* d_out, int out_size, void* d_ws, size_t ws_size,
                              hipStream_t stream) {
    const float* x   = (const float*)d_in[0];
    const float* ea  = (const float*)d_in[1];
    const float* cW  = (const float*)d_in[2];
    const float* cb  = (const float*)d_in[3];
    const float* gam = (const float*)d_in[4];
    const float* bet = (const float*)d_in[5];
    const float* Wih = (const float*)d_in[6];
    const float* Whh = (const float*)d_in[7];
    const float* bih = (const float*)d_in[8];
    const float* bhh = (const float*)d_in[9];
    const float* lW  = (const float*)d_in[10];
    const float* lb  = (const float*)d_in[11];
    const int*   ei  = (const int*)d_in[12];
    float* out = (float*)d_out;

    // Workspace (72.0 MB):
    // [bn_acc 40KB][Wp 2.75MB][X 15.7MB][big 53.5MB]
    // big phase 1: y_pre @0 (31.5MB), part @32MB (1.97MB)
    // big phase 2: c @0 (2MB), cnt @2MB (4KB), h_all @2MB+4KB (49 x 1MB)
    char* ws = (char*)d_ws;
    float* bn_acc = (float*)ws;
    bf16*  Wp     = (bf16*)(ws + 40960);
    bf16*  X      = (bf16*)(ws + 2793472);
    char*  big    = ws + 18522112;
    float* y_pre  = (float*)big;
    float* part   = (float*)(big + 33554432);
    float* c_buf  = (float*)big;
    int*   cnt    = (int*)(big + 2097152);
    bf16*  h_all  = (bf16*)(big + 2101248);

    (void)hipFuncSetAttribute((const void*)k_lstm,
                              hipFuncAttributeMaxDynamicSharedMemorySize, 65536);

    static int nblk = 0;                 // persistent grid: 2 blocks/CU resident
    if (nblk == 0) {
        int dev = 0, ncu = 0;
        if (hipGetDevice(&dev) != hipSuccess) dev = 0;
        if (hipDeviceGetAttribute(&ncu, hipDeviceAttributeMultiprocessorCount, dev)
                != hipSuccess || ncu <= 0) ncu = 256;
        nblk = 2*ncu; if (nblk > 512) nblk = 512;
    }

    k_pack<<<5376, 256, 0, stream>>>(Wih, Whh, Wp);
    k_graph<<<NG_/4, 256, 0, stream>>>(x, ea, cW, cb, ei, y_pre, part);
    k_stats<<<B_, 64, 0, stream>>>(part, bn_acc);
    k_bn<<<NF_/256, 256, 0, stream>>>(y_pre, bn_acc, gam, bet, X);
    // zero c (2MB) + cnt (4KB) + h_all slab 0 (1MB) = 196864 float4
    k_zero<<<769, 256, 0, stream>>>((float4*)big, 196864);
    k_lstm<<<nblk, 256, 65536, stream>>>(X, Wp, bih, bhh, h_all, c_buf, cnt);
    k_final<<<B_, 256, 0, stream>>>(h_all + (size_t)B_*H_, lW, lb, out);
}

// Round 2
// 753.728 us; speedup vs baseline: 3.0681x; 3.0681x over previous
//
#include <hip/hip_runtime.h>
#include <hip/hip_bf16.h>

// ECLGCNN: ChebConv(K=3) on 49152 disjoint 32-node graphs -> per-sample BN ->
// sigmoid -> LSTM(48 steps, H=512) -> linear head. Inputs fp32, output fp32.
// R9: repair R8's persistent-LSTM sync. R8 stalled 36us/step on (a) 16 flag
// counters packed in ONE 64B line (512 agent RMWs + ~1e5 polls/step serialize
// at MALL) and (b) RELEASE fetch_add emitting buffer_wbl2 (full L2 writeback)
// 512x/step. Fix: 128B-padded counters; h written via agent-scope RELAXED
// atomic stores (write-through to coherent MALL, no dirty L2) so the flag add
// can be RELAXED (no wbl2). Ordering: __syncthreads drains vmcnt before add.

#define B_    1024
#define T_    48
#define NPG_  32
#define F_    5
#define H_    512
#define EPG_  256
#define NG_   (B_*T_)          // 49152 graphs
#define N_    (B_*T_*NPG_)     // 1572864 nodes
#define E_    (B_*T_*EPG_)     // 12582912 edges
#define NF_   (N_*F_)          // 7864320

typedef __bf16 bf16x8 __attribute__((ext_vector_type(8)));
typedef float  f32x4  __attribute__((ext_vector_type(4)));
typedef __hip_bfloat16 bf16;

__device__ __forceinline__ float sigm(float x)   { return 1.0f/(1.0f+__expf(-x)); }
__device__ __forceinline__ float tanh_f(float x) { return 2.0f/(1.0f+__expf(-2.0f*x)) - 1.0f; }

__device__ __forceinline__ void gl_lds16(const void* g, void* l) {
    __builtin_amdgcn_global_load_lds((const __attribute__((address_space(1))) unsigned int*)g,
                                     (__attribute__((address_space(3))) unsigned int*)l, 16, 0, 0);
}

// write-through bf16 store: coherent at agent scope (MALL), no local-L2 dirty line
__device__ __forceinline__ void store_h_wt(bf16* p, float v) {
    bf16 b = __float2bfloat16(v);
    unsigned short us; __builtin_memcpy(&us, &b, 2);
    __hip_atomic_store(reinterpret_cast<unsigned short*>(p), us,
                       __ATOMIC_RELAXED, __HIP_MEMORY_SCOPE_AGENT);
}

__global__ __launch_bounds__(256) void k_zero(float4* p, int n) {
    int i = blockIdx.x*256 + threadIdx.x;
    if (i < n) p[i] = make_float4(0.f, 0.f, 0.f, 0.f);
}

// Pack W' = [Wih | Whh] row-major [2048][672], fp32 -> bf16.
__global__ __launch_bounds__(256) void k_pack(const float* __restrict__ Wih,
                                              const float* __restrict__ Whh,
                                              bf16* __restrict__ Wp) {
    int i = blockIdx.x*256 + threadIdx.x;           // < 2048*672
    int r = i / 672, c = i - r*672;
    float v = (c < 160) ? Wih[r*160 + c] : Whh[r*512 + (c-160)];
    Wp[i] = __float2bfloat16(v);
}

// Graph-per-wave ChebConv: 4 graphs per 256-thread block.
__global__ __launch_bounds__(256) void k_graph(
    const float* __restrict__ x, const float* __restrict__ ea,
    const float* __restrict__ cW, const float* __restrict__ cb,
    const int* __restrict__ ei, float* __restrict__ y_pre,
    float* __restrict__ part)
{
    const int tid = threadIdx.x, w = tid >> 6, lane = tid & 63;
    const int g = blockIdx.x*4 + w;
    __shared__ float Msh[4][1056];                  // Mt[d][s], row stride 33
    __shared__ float dinv[4][32];
    __shared__ float T0s[4][160], T1s[4][160], T2s[4][160];
    __shared__ __align__(16) float Spad[4][256];    // scaled vec, rows padded to 8
    __shared__ float Wsh[75], bsh[5];
    float* mt = Msh[w];

    if (lane < 75) Wsh[lane] = cW[lane];
    if (lane < 5)  bsh[lane] = cb[lane];
    const float4 ew = *reinterpret_cast<const float4*>(ea + (size_t)g*256 + lane*4);
    const int4   es = *reinterpret_cast<const int4*>(ei + (size_t)g*256 + lane*4);
    const int4   ed = *reinterpret_cast<const int4*>(ei + (size_t)E_ + (size_t)g*256 + lane*4);
    T0s[w][lane]      = x[(size_t)g*160 + lane];
    T0s[w][64+lane]   = x[(size_t)g*160 + 64 + lane];
    if (lane < 32) T0s[w][128+lane] = x[(size_t)g*160 + 128 + lane];
    for (int i = lane; i < 1056; i += 64) mt[i] = 0.f;
    __syncthreads();
    atomicAdd(&mt[(ed.x & 31)*33 + (es.x & 31)], ew.x);
    atomicAdd(&mt[(ed.y & 31)*33 + (es.y & 31)], ew.y);
    atomicAdd(&mt[(ed.z & 31)*33 + (es.z & 31)], ew.z);
    atomicAdd(&mt[(ed.w & 31)*33 + (es.w & 31)], ew.w);
    __syncthreads();
    if (lane < 32) {                                // deg[s] = sum_d Mt[d][s]
        float dg = 0.f;
        #pragma unroll
        for (int d = 0; d < 32; ++d) dg += mt[d*33 + lane];
        dinv[w][lane] = dg > 0.f ? rsqrtf(dg) : 0.f;
    }
    __syncthreads();
    for (int i = lane; i < 160; i += 64) Spad[w][(i/5)*8 + (i%5)] = dinv[w][i/5]*T0s[w][i];
    __syncthreads();
    if (lane < 32) {                                // T1 = -dinv .* (Mt @ S0)
        const int d = lane;
        float a0=0.f,a1=0.f,a2=0.f,a3=0.f,a4=0.f;
        #pragma unroll 4
        for (int s = 0; s < 32; ++s) {
            const float m = mt[d*33+s];
            const float4 sv = *reinterpret_cast<const float4*>(&Spad[w][s*8]);
            const float s4 = Spad[w][s*8+4];
            a0 += m*sv.x; a1 += m*sv.y; a2 += m*sv.z; a3 += m*sv.w; a4 += m*s4;
        }
        const float sc = -dinv[w][d];
        T1s[w][d*5+0]=sc*a0; T1s[w][d*5+1]=sc*a1; T1s[w][d*5+2]=sc*a2;
        T1s[w][d*5+3]=sc*a3; T1s[w][d*5+4]=sc*a4;
    }
    __syncthreads();
    for (int i = lane; i < 160; i += 64) Spad[w][(i/5)*8 + (i%5)] = dinv[w][i/5]*T1s[w][i];
    __syncthreads();
    if (lane < 32) {                                // T2 = 2 L~ T1 - T0
        const int d = lane;
        float a0=0.f,a1=0.f,a2=0.f,a3=0.f,a4=0.f;
        #pragma unroll 4
        for (int s = 0; s < 32; ++s) {
            const float m = mt[d*33+s];
            const float4 sv = *reinterpret_cast<const float4*>(&Spad[w][s*8]);
            const float s4 = Spad[w][s*8+4];
            a0 += m*sv.x; a1 += m*sv.y; a2 += m*sv.z; a3 += m*sv.w; a4 += m*s4;
        }
        const float sc = -2.f*dinv[w][d];
        T2s[w][d*5+0]=sc*a0-T0s[w][d*5+0]; T2s[w][d*5+1]=sc*a1-T0s[w][d*5+1];
        T2s[w][d*5+2]=sc*a2-T0s[w][d*5+2]; T2s[w][d*5+3]=sc*a3-T0s[w][d*5+3];
        T2s[w][d*5+4]=sc*a4-T0s[w][d*5+4];
    }
    __syncthreads();
    float* vb = mt;                                 // reuse adjacency LDS for y
    for (int i = lane; i < 160; i += 64) {
        const int n = i/5, f = i - 5*n;
        float v = bsh[f];
        #pragma unroll
        for (int c = 0; c < 5; ++c)
            v += T0s[w][n*5+c]*Wsh[c*5+f] + T1s[w][n*5+c]*Wsh[25+c*5+f] + T2s[w][n*5+c]*Wsh[50+c*5+f];
        y_pre[(size_t)g*160 + i] = v;
        vb[i] = v;
    }
    __syncthreads();
    if (lane < 10) {                                // per-graph BN partials
        const int f = lane % 5; const bool sq = lane >= 5;
        float sm = 0.f;
        #pragma unroll 8
        for (int n = 0; n < 32; ++n) { float v = vb[n*5+f]; sm += sq ? v*v : v; }
        part[(size_t)g*10 + lane] = sm;
    }
}

__global__ __launch_bounds__(64) void k_stats(const float* __restrict__ part,
                                              float* __restrict__ bn_acc) {
    const int b = blockIdx.x, tid = threadIdx.x;
    if (tid < 10) {
        float s = 0.f;
        for (int j = 0; j < T_; ++j) s += part[((size_t)b*T_ + j)*10 + tid];
        bn_acc[b*10 + tid] = s;
    }
}

__global__ __launch_bounds__(256) void k_bn(
    const float* __restrict__ y_pre, const float* __restrict__ bn_acc,
    const float* __restrict__ gamma, const float* __restrict__ beta,
    bf16* __restrict__ X)
{
    const int i = blockIdx.x*256 + threadIdx.x;
    const int b   = i / 7680;
    const int rem = i - b*7680;
    const int t   = rem / 160;
    const int pf  = rem - t*160;
    const int f   = pf % 5;
    const float inv  = 1.0f/1536.0f;
    const float mean = bn_acc[b*10+f]*inv;
    const float var  = bn_acc[b*10+5+f]*inv - mean*mean;
    const float v = gamma[f]*(y_pre[i]-mean)*rsqrtf(var+1e-5f) + beta[f];
    X[((size_t)t*B_ + b)*160 + pf] = __float2bfloat16(sigm(v));
}

// ---- persistent LSTM: 3-phase staged GEMM per step, flag-sync between steps ----
// 512 tiles (16 m-groups x 32 u-tiles). Tile (mi,ui): 64 batch rows x 64 gate
// rows. h stored in fresh slabs h_all[t] (49 x 1MB), written WRITE-THROUGH
// (agent-relaxed atomic stores) so consumers' clean L2s can't go stale and no
// wbl2 is ever needed. Flags: one 128B-padded counter per (t, m-group);
// producers RELAXED fetch_add after vmcnt drain; consumers spin relaxed+sleep,
// overlapped with the h-independent X-phase staging. c_buf is block-private
// (same block owns the same tile every step) -> local L2, no coherence.

__device__ __forceinline__ void stage_A(const char* gbase, int strideB, char* lds,
                                        int gpr, int xmask, int nper, int tid) {
    for (int p = 0; p < nper; ++p) {
        const int S = p*256 + tid;
        const int row = S / gpr;
        const int col = (S - row*gpr) ^ (row & xmask);
        gl_lds16(gbase + (size_t)row*strideB + (size_t)col*16, lds + (size_t)S*16);
    }
}

__device__ __forceinline__ void stage_W(const char* Wbase, char* lds,
                                        int gpr, int xmask, int nper, int tid, int u0) {
    for (int p = 0; p < nper; ++p) {
        const int S = p*256 + tid;
        const int row = S / gpr;
        const int col = (S - row*gpr) ^ (row & xmask);
        const int wrow = ((row >> 4) << 9) + u0 + (row & 15);
        gl_lds16(Wbase + (size_t)wrow*1344 + (size_t)col*16, lds + (size_t)S*16);
    }
}

__device__ __forceinline__ void mfma_phase(const char* Al, const char* Wl, int gpr,
                                           int xmask, int nkk, int arow, int lo,
                                           int quad, f32x4 acc[4]) {
    for (int kk = 0; kk < nkk; ++kk) {
        const int kq = kk*4 + quad;
        const bf16x8 a = *reinterpret_cast<const bf16x8*>(
            Al + ((size_t)arow*gpr + (kq ^ (arow & xmask)))*16);
        #pragma unroll
        for (int g = 0; g < 4; ++g) {
            const int wr = g*16 + lo;
            const bf16x8 b = *reinterpret_cast<const bf16x8*>(
                Wl + ((size_t)wr*gpr + (kq ^ (wr & xmask)))*16);
            acc[g] = __builtin_amdgcn_mfma_f32_16x16x32_bf16(a, b, acc[g], 0, 0, 0);
        }
    }
}

__global__ __launch_bounds__(256, 2) void k_lstm(
    const bf16* __restrict__ X,  const bf16* __restrict__ Wp,
    const float* __restrict__ bih, const float* __restrict__ bhh,
    bf16* __restrict__ h_all, float* __restrict__ c_buf,
    int* __restrict__ cnt)
{
    extern __shared__ char sm[];
    char* Al = sm;
    char* Wl = sm + 32768;
    const int tid = threadIdx.x;
    const int lane = tid & 63, w = tid >> 6;
    const int lo = lane & 15, quad = lane >> 4;
    const int arow = w*16 + lo;
    const char* Wb = (const char*)Wp;

    for (int t = 0; t < T_; ++t) {
        const char* Hin = (const char*)(h_all + (size_t)t*B_*H_);
        bf16* h_out = h_all + (size_t)(t+1)*B_*H_;
        for (int tile = blockIdx.x; tile < 512; tile += gridDim.x) {
            const int mi = tile >> 5, ui = tile & 31;
            const int m0 = mi*64, u0 = ui*16;
            const char* Xb = (const char*)X + (size_t)t*B_*320 + (size_t)m0*320;
            const char* Hb = Hin + (size_t)m0*1024;
            f32x4 acc[4] = {};

            // phase 0: X part (K=160) -- independent of h, overlaps the wait
            stage_A(Xb, 320, Al, 20, 3, 5, tid);
            stage_W(Wb, Wl, 20, 3, 5, tid, u0);
            const int u = u0 + lo;
            const float bI = bih[u]      + bhh[u];
            const float bF = bih[512+u]  + bhh[512+u];
            const float bG = bih[1024+u] + bhh[1024+u];
            const float bO = bih[1536+u] + bhh[1536+u];
            if (t > 0 && tid == 0) {                 // wait h producers of step t-1
                int* p = cnt + (size_t)((t-1)*16 + mi)*32;
                while (__hip_atomic_load(p, __ATOMIC_RELAXED, __HIP_MEMORY_SCOPE_AGENT) < 32)
                    __builtin_amdgcn_s_sleep(4);
            }
            __syncthreads();                          // drains vmcnt: LDS ready
            mfma_phase(Al, Wl, 20, 3, 5, arow, lo, quad, acc);
            __syncthreads();
            // phase 1: h[0:256)
            stage_A(Hb, 1024, Al, 32, 7, 8, tid);
            stage_W(Wb + 320, Wl, 32, 7, 8, tid, u0);
            __syncthreads();
            mfma_phase(Al, Wl, 32, 7, 8, arow, lo, quad, acc);
            __syncthreads();
            // phase 2: h[256:512)
            stage_A(Hb + 512, 1024, Al, 32, 7, 8, tid);
            stage_W(Wb + 832, Wl, 32, 7, 8, tid, u0);
            __syncthreads();
            mfma_phase(Al, Wl, 32, 7, 8, arow, lo, quad, acc);

            #pragma unroll
            for (int r = 0; r < 4; ++r) {
                const int m = m0 + w*16 + quad*4 + r;
                const int idx = m*512 + u;
                const float iv = acc[0][r] + bI;
                const float fv = acc[1][r] + bF;
                const float gv = acc[2][r] + bG;
                const float ov = acc[3][r] + bO;
                const float c_new = sigm(fv)*c_buf[idx] + sigm(iv)*tanh_f(gv);
                c_buf[idx] = c_new;
                store_h_wt(&h_out[idx], sigm(ov)*tanh_f(c_new));
            }
            __syncthreads();                          // drains vmcnt: h at MALL
            if (tid == 0)                             // relaxed: no L2 writeback
                __hip_atomic_fetch_add(cnt + (size_t)(t*16 + mi)*32, 1,
                                       __ATOMIC_RELAXED, __HIP_MEMORY_SCOPE_AGENT);
        }
    }
}

// out[b,j] = sigmoid( sum_{t,u} sigm(h[t,b,u]) * lin_W[j, t*512+u] + lin_b[j] )
__global__ __launch_bounds__(256) void k_final(
    const bf16* __restrict__ hs, const float* __restrict__ lW,
    const float* __restrict__ lb, float* __restrict__ out)
{
    const int b = blockIdx.x, tid = threadIdx.x;
    const int u = tid*2;
    float a0=0.f, a1=0.f, a2=0.f, a3=0.f;
    for (int t = 0; t < T_; ++t) {
        const bf16* hr = hs + ((size_t)t*B_ + b)*H_ + u;
        const float h0 = sigm((float)hr[0]), h1 = sigm((float)hr[1]);
        const int o = t*H_ + u;
        a0 += h0*lW[o]         + h1*lW[o+1];
        a1 += h0*lW[24576+o]   + h1*lW[24576+o+1];
        a2 += h0*lW[49152+o]   + h1*lW[49152+o+1];
        a3 += h0*lW[73728+o]   + h1*lW[73728+o+1];
    }
    #pragma unroll
    for (int off = 32; off > 0; off >>= 1) {
        a0 += __shfl_down(a0, off, 64);
        a1 += __shfl_down(a1, off, 64);
        a2 += __shfl_down(a2, off, 64);
        a3 += __shfl_down(a3, off, 64);
    }
    __shared__ float red[4][4];
    const int wave = tid >> 6, lane = tid & 63;
    if (lane == 0) { red[0][wave]=a0; red[1][wave]=a1; red[2][wave]=a2; red[3][wave]=a3; }
    __syncthreads();
    if (tid < 4) {
        float s = red[tid][0]+red[tid][1]+red[tid][2]+red[tid][3] + lb[tid];
        out[b*4 + tid] = sigm(s);
    }
}

extern "C" void kernel_launch(void* const* d_in, const int* in_sizes, int n_in,
                              void* d_out, int out_size, void* d_ws, size_t ws_size,
                              hipStream_t stream) {
    const float* x   = (const float*)d_in[0];
    const float* ea  = (const float*)d_in[1];
    const float* cW  = (const float*)d_in[2];
    const float* cb  = (const float*)d_in[3];
    const float* gam = (const float*)d_in[4];
    const float* bet = (const float*)d_in[5];
    const float* Wih = (const float*)d_in[6];
    const float* Whh = (const float*)d_in[7];
    const float* bih = (const float*)d_in[8];
    const float* bhh = (const float*)d_in[9];
    const float* lW  = (const float*)d_in[10];
    const float* lb  = (const float*)d_in[11];
    const int*   ei  = (const int*)d_in[12];
    float* out = (float*)d_out;

    // Workspace (~69 MB):
    // [bn_acc 40KB][Wp 2.75MB][X 15.7MB][big 51.2MB]
    // big phase 1: y_pre @0 (31.5MB), part @32MB (1.97MB)
    // big phase 2: cnt @0 (128KB, 48x16 counters, 128B-padded),
    //              c @128KB (2MB), h_all @128KB+2MB (49 x 1MB)
    char* ws = (char*)d_ws;
    float* bn_acc = (float*)ws;
    bf16*  Wp     = (bf16*)(ws + 40960);
    bf16*  X      = (bf16*)(ws + 2793472);
    char*  big    = ws + 18522112;
    float* y_pre  = (float*)big;
    float* part   = (float*)(big + 33554432);
    int*   cnt    = (int*)big;
    float* c_buf  = (float*)(big + 131072);
    bf16*  h_all  = (bf16*)(big + 131072 + 2097152);

    (void)hipFuncSetAttribute((const void*)k_lstm,
                              hipFuncAttributeMaxDynamicSharedMemorySize, 65536);

    static int nblk = 0;                 // persistent grid: 2 blocks/CU resident
    if (nblk == 0) {
        int dev = 0, ncu = 0;
        if (hipGetDevice(&dev) != hipSuccess) dev = 0;
        if (hipDeviceGetAttribute(&ncu, hipDeviceAttributeMultiprocessorCount, dev)
                != hipSuccess || ncu <= 0) ncu = 256;
        nblk = 2*ncu; if (nblk > 512) nblk = 512;
    }

    k_pack<<<5376, 256, 0, stream>>>(Wih, Whh, Wp);
    k_graph<<<NG_/4, 256, 0, stream>>>(x, ea, cW, cb, ei, y_pre, part);
    k_stats<<<B_, 64, 0, stream>>>(part, bn_acc);
    k_bn<<<NF_/256, 256, 0, stream>>>(y_pre, bn_acc, gam, bet, X);
    // zero cnt (128KB) + c (2MB) + h_all slab 0 (1MB) = 204800 float4
    k_zero<<<800, 256, 0, stream>>>((float4*)big, 204800);
    k_lstm<<<nblk, 256, 65536, stream>>>(X, Wp, bih, bhh, h_all, c_buf, cnt);
    k_final<<<B_, 256, 0, stream>>>(h_all + (size_t)B_*H_, lW, lb, out);
}